// Round 1
// baseline (3170.743 us; speedup 1.0000x reference)
//
#include <hip/hip_runtime.h>
#include <hip/hip_bf16.h>

// Problem constants (match reference)
#define NN 100000   // nodes
#define NE 640000   // edges
#define NF 128      // input features
#define NG 64       // graphs
#define BN_EPS 1e-5f

#define BS 256      // block size

static inline int cdiv(long long a, int b) { return (int)((a + b - 1) / b); }

// ---------------- degree: deg[s] += 1 for non-self-loop edges ----------------
__global__ void deg_kernel(const int* __restrict__ src, const int* __restrict__ dst,
                           float* __restrict__ deg, int E) {
    int e = blockIdx.x * blockDim.x + threadIdx.x;
    if (e >= E) return;
    int s = src[e], d = dst[e];
    if (s != d) unsafeAtomicAdd(&deg[s], 1.0f);
}

// ---------------- edge weights: w[e] = -dinv[src]*dinv[dst] ----------------
__global__ void wgt_kernel(const int* __restrict__ src, const int* __restrict__ dst,
                           const float* __restrict__ deg, float* __restrict__ w, int E) {
    int e = blockIdx.x * blockDim.x + threadIdx.x;
    if (e >= E) return;
    int s = src[e], d = dst[e];
    float wv = 0.0f;
    if (s != d) {
        float ds_ = deg[s], dd = deg[d];
        float a = ds_ > 0.0f ? rsqrtf(ds_) : 0.0f;
        float b = dd  > 0.0f ? rsqrtf(dd)  : 0.0f;
        wv = -a * b;
    }
    w[e] = wv;
}

// ---------------- gemm3: U = x@W2, T = x@W1, S = x@(W0-W2) ----------------
// W layout: [3][FI][FO] row-major
template <int FI, int FO>
__global__ void gemm3_kernel(const float* __restrict__ x, const float* __restrict__ W,
                             float* __restrict__ U, float* __restrict__ T, float* __restrict__ S,
                             int N) {
    int idx = blockIdx.x * blockDim.x + threadIdx.x;
    if (idx >= N * FO) return;
    int node = idx / FO;        // FO is pow2 -> shift
    int c    = idx & (FO - 1);
    const float* xr = x + (long long)node * FI;
    const float* w0 = W + c;
    const float* w1 = W + FI * FO + c;
    const float* w2 = W + 2 * FI * FO + c;
    float a0 = 0.f, a1 = 0.f, a2 = 0.f;
#pragma unroll 8
    for (int k = 0; k < FI; k++) {
        float xv = xr[k];
        a0 = fmaf(xv, w0[k * FO], a0);
        a1 = fmaf(xv, w1[k * FO], a1);
        a2 = fmaf(xv, w2[k * FO], a2);
    }
    U[idx] = a2;
    T[idx] = a1;
    S[idx] = a0 - a2;
}

// ---------------- prop: out[dst] += scale * w[e] * xin[src]  (float4 chunks) ----------------
template <int FO>
__global__ void prop_kernel(const float* __restrict__ xin, float* __restrict__ out,
                            const int* __restrict__ src, const int* __restrict__ dst,
                            const float* __restrict__ w, float scale, int E) {
    constexpr int PER = FO / 4;
    long long idx = (long long)blockIdx.x * blockDim.x + threadIdx.x;
    if (idx >= (long long)E * PER) return;
    int e = (int)(idx / PER);               // PER is pow2 -> shift
    int f = ((int)idx & (PER - 1)) * 4;
    float wv = w[e];
    if (wv == 0.0f) return;
    wv *= scale;
    int s = src[e], d = dst[e];
    const float4 xv = *(const float4*)(xin + (long long)s * FO + f);
    float* o = out + (long long)d * FO + f;
    unsafeAtomicAdd(o + 0, wv * xv.x);
    unsafeAtomicAdd(o + 1, wv * xv.y);
    unsafeAtomicAdd(o + 2, wv * xv.z);
    unsafeAtomicAdd(o + 3, wv * xv.w);
}

// ---------------- epilogue: h = leaky_relu(BN(S + b)) ----------------
template <int FO>
__global__ void epi_kernel(const float* __restrict__ S, const float* __restrict__ b,
                           const float* __restrict__ g, const float* __restrict__ be,
                           const float* __restrict__ m, const float* __restrict__ vv,
                           float* __restrict__ h, int N) {
    int idx = blockIdx.x * blockDim.x + threadIdx.x;
    if (idx >= N * FO) return;
    int f = idx & (FO - 1);
    float val = S[idx] + b[f];
    float y = (val - m[f]) * rsqrtf(vv[f] + BN_EPS) * g[f] + be[f];
    h[idx] = y > 0.0f ? y : 0.01f * y;
}

// ---------------- mean pool (sums + counts via atomics) ----------------
__global__ void pool_kernel(const float* __restrict__ h3, const int* __restrict__ batch,
                            float* __restrict__ pool, float* __restrict__ cnt, int N) {
    int idx = blockIdx.x * blockDim.x + threadIdx.x;
    if (idx >= N * 16) return;
    int node = idx >> 4;
    int f    = idx & 15;
    int g = batch[node];
    unsafeAtomicAdd(&pool[g * 16 + f], h3[idx]);
    if (f == 0) unsafeAtomicAdd(&cnt[g], 1.0f);
}

// ---------------- final linear head: out[g,c] = (pool[g,:]/cnt[g]) . lw[c,:] + lb[c] ----------------
__global__ void final_kernel(const float* __restrict__ pool, const float* __restrict__ cnt,
                             const float* __restrict__ lw, const float* __restrict__ lb,
                             float* __restrict__ out) {
    int idx = threadIdx.x;
    if (idx >= NG * 2) return;
    int g = idx >> 1;
    int c = idx & 1;
    float inv = 1.0f / fmaxf(cnt[g], 1.0f);
    float acc = 0.0f;
#pragma unroll
    for (int f = 0; f < 16; f++) acc += pool[g * 16 + f] * lw[c * 16 + f];
    out[idx] = acc * inv + lb[c];
}

extern "C" void kernel_launch(void* const* d_in, const int* in_sizes, int n_in,
                              void* d_out, int out_size, void* d_ws, size_t ws_size,
                              hipStream_t stream) {
    const float* x    = (const float*)d_in[0];
    const int*   ei   = (const int*)d_in[1];
    const int*   batch= (const int*)d_in[2];
    const float* W1 = (const float*)d_in[3];
    const float* b1 = (const float*)d_in[4];
    const float* g1 = (const float*)d_in[5];
    const float* be1= (const float*)d_in[6];
    const float* m1 = (const float*)d_in[7];
    const float* v1 = (const float*)d_in[8];
    const float* W2 = (const float*)d_in[9];
    const float* b2 = (const float*)d_in[10];
    const float* g2 = (const float*)d_in[11];
    const float* be2= (const float*)d_in[12];
    const float* m2 = (const float*)d_in[13];
    const float* v2 = (const float*)d_in[14];
    const float* W3 = (const float*)d_in[15];
    const float* b3 = (const float*)d_in[16];
    const float* g3 = (const float*)d_in[17];
    const float* be3= (const float*)d_in[18];
    const float* m3 = (const float*)d_in[19];
    const float* v3 = (const float*)d_in[20];
    const float* lw = (const float*)d_in[21];
    const float* lb = (const float*)d_in[22];

    const int* src = ei;            // edge_index[0]
    const int* dst = ei + NE;       // edge_index[1]

    float* ws = (float*)d_ws;
    // workspace layout (floats)
    size_t off = 0;
    float* deg = ws + off; off += NN;                 // N
    float* w   = ws + off; off += NE;                 // E
    float* B0  = ws + off; off += (size_t)NN * 64;    // U
    float* B1  = ws + off; off += (size_t)NN * 64;    // T
    float* B2  = ws + off; off += (size_t)NN * 64;    // S
    float* B3  = ws + off; off += (size_t)NN * 64;    // h
    float* pool= ws + off; off += NG * 16;
    float* cnt = ws + off; off += NG;

    // zero-init deg and pool/cnt
    hipMemsetAsync(deg, 0, NN * sizeof(float), stream);
    hipMemsetAsync(pool, 0, (NG * 16 + NG) * sizeof(float), stream);

    // edge weights
    deg_kernel<<<cdiv(NE, BS), BS, 0, stream>>>(src, dst, deg, NE);
    wgt_kernel<<<cdiv(NE, BS), BS, 0, stream>>>(src, dst, deg, w, NE);

    // ---- layer 1: 128 -> 64 ----
    gemm3_kernel<128, 64><<<cdiv((long long)NN * 64, BS), BS, 0, stream>>>(x, W1, B0, B1, B2, NN);
    prop_kernel<64><<<cdiv((long long)NE * 16, BS), BS, 0, stream>>>(B0, B1, src, dst, w, 2.0f, NE);
    prop_kernel<64><<<cdiv((long long)NE * 16, BS), BS, 0, stream>>>(B1, B2, src, dst, w, 1.0f, NE);
    epi_kernel<64><<<cdiv((long long)NN * 64, BS), BS, 0, stream>>>(B2, b1, g1, be1, m1, v1, B3, NN);

    // ---- layer 2: 64 -> 32 ----
    gemm3_kernel<64, 32><<<cdiv((long long)NN * 32, BS), BS, 0, stream>>>(B3, W2, B0, B1, B2, NN);
    prop_kernel<32><<<cdiv((long long)NE * 8, BS), BS, 0, stream>>>(B0, B1, src, dst, w, 2.0f, NE);
    prop_kernel<32><<<cdiv((long long)NE * 8, BS), BS, 0, stream>>>(B1, B2, src, dst, w, 1.0f, NE);
    epi_kernel<32><<<cdiv((long long)NN * 32, BS), BS, 0, stream>>>(B2, b2, g2, be2, m2, v2, B3, NN);

    // ---- layer 3: 32 -> 16 ----
    gemm3_kernel<32, 16><<<cdiv((long long)NN * 16, BS), BS, 0, stream>>>(B3, W3, B0, B1, B2, NN);
    prop_kernel<16><<<cdiv((long long)NE * 4, BS), BS, 0, stream>>>(B0, B1, src, dst, w, 2.0f, NE);
    prop_kernel<16><<<cdiv((long long)NE * 4, BS), BS, 0, stream>>>(B1, B2, src, dst, w, 1.0f, NE);
    epi_kernel<16><<<cdiv((long long)NN * 16, BS), BS, 0, stream>>>(B2, b3, g3, be3, m3, v3, B3, NN);

    // ---- pool + head ----
    pool_kernel<<<cdiv((long long)NN * 16, BS), BS, 0, stream>>>(B3, batch, pool, cnt, NN);
    final_kernel<<<1, 128, 0, stream>>>(pool, cnt, lw, lb, (float*)d_out);
}

// Round 2
// 954.544 us; speedup vs baseline: 3.3217x; 3.3217x over previous
//
#include <hip/hip_runtime.h>
#include <hip/hip_bf16.h>

// Problem constants (match reference)
#define NN 100000   // nodes
#define NE 640000   // edges
#define NG 64       // graphs
#define BN_EPS 1e-5f

#define BS 256      // block size
#define SCAN_BS 1024
#define NB_SCAN ((NN + SCAN_BS - 1) / SCAN_BS)   // 98
#define PNPB 2048   // nodes per block in pool

static inline int cdiv(long long a, int b) { return (int)((a + b - 1) / b); }

// ---------------- degree: deg[s] += 1 for non-self-loop edges ----------------
__global__ void deg_kernel(const int* __restrict__ src, const int* __restrict__ dst,
                           float* __restrict__ deg, int E) {
    int e = blockIdx.x * blockDim.x + threadIdx.x;
    if (e >= E) return;
    int s = src[e], d = dst[e];
    if (s != d) unsafeAtomicAdd(&deg[s], 1.0f);
}

// ---- edge weights + CSR histogram: w[e] = -dinv[src]*dinv[dst]; cnt_n[dst]++ if w!=0 ----
__global__ void wgt_hist_kernel(const int* __restrict__ src, const int* __restrict__ dst,
                                const float* __restrict__ deg, float* __restrict__ w,
                                int* __restrict__ cnt_n, int E) {
    int e = blockIdx.x * blockDim.x + threadIdx.x;
    if (e >= E) return;
    int s = src[e], d = dst[e];
    float wv = 0.0f;
    if (s != d) {
        float ds_ = deg[s], dd = deg[d];
        float a = ds_ > 0.0f ? rsqrtf(ds_) : 0.0f;
        float b = dd  > 0.0f ? rsqrtf(dd)  : 0.0f;
        wv = -a * b;
    }
    w[e] = wv;
    if (wv != 0.0f) atomicAdd(&cnt_n[d], 1);
}

// ---------------- 3-kernel exclusive scan of cnt_n -> row_start ----------------
__global__ void scan1_kernel(const int* __restrict__ cnt, int* __restrict__ excl,
                             int* __restrict__ bsum, int N) {
    __shared__ int s[SCAN_BS];
    int t = threadIdx.x;
    int i = blockIdx.x * SCAN_BS + t;
    int v = (i < N) ? cnt[i] : 0;
    s[t] = v;
    __syncthreads();
    for (int off = 1; off < SCAN_BS; off <<= 1) {
        int add = (t >= off) ? s[t - off] : 0;
        __syncthreads();
        s[t] += add;
        __syncthreads();
    }
    if (i < N) excl[i] = s[t] - v;   // exclusive
    if (t == SCAN_BS - 1) bsum[blockIdx.x] = s[t];
}

__global__ void scan2_kernel(int* __restrict__ bsum, int* __restrict__ total, int NB) {
    __shared__ int s[128];
    int t = threadIdx.x;
    int v = (t < NB) ? bsum[t] : 0;
    s[t] = v;
    __syncthreads();
    for (int off = 1; off < 128; off <<= 1) {
        int add = (t >= off) ? s[t - off] : 0;
        __syncthreads();
        s[t] += add;
        __syncthreads();
    }
    if (t < NB) bsum[t] = s[t] - v;  // exclusive
    if (t == 127) *total = s[127];
}

__global__ void scan3_kernel(int* __restrict__ excl, const int* __restrict__ bsum, int N) {
    int i = blockIdx.x * blockDim.x + threadIdx.x;
    if (i < N) excl[i] += bsum[i >> 10];   // SCAN_BS = 1024
}

// ---------------- scatter edges into CSR slots ----------------
__global__ void scatter_kernel(const int* __restrict__ src, const int* __restrict__ dst,
                               const float* __restrict__ w, const int* __restrict__ row_start,
                               int* __restrict__ fill, int* __restrict__ col,
                               float* __restrict__ val, int E) {
    int e = blockIdx.x * blockDim.x + threadIdx.x;
    if (e >= E) return;
    float wv = w[e];
    if (wv == 0.0f) return;
    int d = dst[e];
    int pos = row_start[d] + atomicAdd(&fill[d], 1);
    col[pos] = src[e];
    val[pos] = wv;
}

// ---------------- gemm3: U = x@W2, T = x@W1, S = x@(W0-W2) ----------------
// W layout: [3][FI][FO] row-major
template <int FI, int FO>
__global__ void gemm3_kernel(const float* __restrict__ x, const float* __restrict__ W,
                             float* __restrict__ U, float* __restrict__ T, float* __restrict__ S,
                             int N) {
    int idx = blockIdx.x * blockDim.x + threadIdx.x;
    if (idx >= N * FO) return;
    int node = idx / FO;
    int c    = idx & (FO - 1);
    const float* xr = x + (size_t)node * FI;
    const float* w0 = W + c;
    const float* w1 = W + FI * FO + c;
    const float* w2 = W + 2 * FI * FO + c;
    float a0 = 0.f, a1 = 0.f, a2 = 0.f;
#pragma unroll 8
    for (int k = 0; k < FI; k++) {
        float xv = xr[k];
        a0 = fmaf(xv, w0[k * FO], a0);
        a1 = fmaf(xv, w1[k * FO], a1);
        a2 = fmaf(xv, w2[k * FO], a2);
    }
    U[idx] = a2;
    T[idx] = a1;
    S[idx] = a0 - a2;
}

// ---------------- propA: inout[i] += 2 * sum_p val[p]*xin[col[p]]  (gather, no atomics) ----
template <int FO>
__global__ void propA_kernel(const float* __restrict__ xin, float* __restrict__ inout,
                             const int* __restrict__ rs, const int* __restrict__ col,
                             const float* __restrict__ val, int N) {
    constexpr int PER = FO / 4;
    int idx = blockIdx.x * blockDim.x + threadIdx.x;
    if (idx >= N * PER) return;
    int i = idx / PER;
    int c = (idx & (PER - 1)) * 4;
    int beg = rs[i], end = rs[i + 1];
    float4 acc = make_float4(0.f, 0.f, 0.f, 0.f);
    for (int p = beg; p < end; ++p) {
        int s = col[p];
        float wv = val[p];
        const float4 xv = *(const float4*)(xin + (size_t)s * FO + c);
        acc.x = fmaf(wv, xv.x, acc.x);
        acc.y = fmaf(wv, xv.y, acc.y);
        acc.z = fmaf(wv, xv.z, acc.z);
        acc.w = fmaf(wv, xv.w, acc.w);
    }
    float4 o = *(const float4*)(inout + (size_t)i * FO + c);
    o.x += 2.0f * acc.x;
    o.y += 2.0f * acc.y;
    o.z += 2.0f * acc.z;
    o.w += 2.0f * acc.w;
    *(float4*)(inout + (size_t)i * FO + c) = o;
}

// ---- propC: h[i] = leaky_relu(BN(S[i] + sum_p val[p]*xin[col[p]] + b)) -- fused epilogue ----
template <int FO>
__global__ void propC_kernel(const float* __restrict__ xin, const float* __restrict__ S,
                             const int* __restrict__ rs, const int* __restrict__ col,
                             const float* __restrict__ val,
                             const float* __restrict__ b, const float* __restrict__ g,
                             const float* __restrict__ be, const float* __restrict__ m,
                             const float* __restrict__ vv,
                             float* __restrict__ h, int N) {
    constexpr int PER = FO / 4;
    int idx = blockIdx.x * blockDim.x + threadIdx.x;
    if (idx >= N * PER) return;
    int i = idx / PER;
    int c = (idx & (PER - 1)) * 4;
    int beg = rs[i], end = rs[i + 1];
    float4 acc = make_float4(0.f, 0.f, 0.f, 0.f);
    for (int p = beg; p < end; ++p) {
        int s = col[p];
        float wv = val[p];
        const float4 xv = *(const float4*)(xin + (size_t)s * FO + c);
        acc.x = fmaf(wv, xv.x, acc.x);
        acc.y = fmaf(wv, xv.y, acc.y);
        acc.z = fmaf(wv, xv.z, acc.z);
        acc.w = fmaf(wv, xv.w, acc.w);
    }
    const float4 sv = *(const float4*)(S + (size_t)i * FO + c);
    float* out = h + (size_t)i * FO + c;
    float4 o;
#pragma unroll
    for (int j = 0; j < 4; j++) {
        int f = c + j;
        float A = g[f] * rsqrtf(vv[f] + BN_EPS);
        float B = be[f] - m[f] * A + b[f] * A;
        float v0 = (j == 0 ? sv.x + acc.x : j == 1 ? sv.y + acc.y : j == 2 ? sv.z + acc.z : sv.w + acc.w);
        float y = v0 * A + B;
        y = y > 0.0f ? y : 0.01f * y;
        (j == 0 ? o.x : j == 1 ? o.y : j == 2 ? o.z : o.w) = y;
    }
    *(float4*)out = o;
}

// ---------------- mean pool: register accum + LDS table + few global atomics ----------------
__global__ void pool2_kernel(const float* __restrict__ h, const int* __restrict__ batch,
                             float* __restrict__ pool, float* __restrict__ cnt, int N) {
    __shared__ float sp[NG * 16];
    __shared__ float sc[NG];
    int t = threadIdx.x;
    for (int i = t; i < NG * 16; i += BS) sp[i] = 0.f;
    for (int i = t; i < NG; i += BS) sc[i] = 0.f;
    __syncthreads();
    int f = t & 15, lane = t >> 4;   // 16 lanes x 16 features
    int base = blockIdx.x * PNPB;
    int nEnd = min(base + PNPB, N);
    float acc = 0.f, cacc = 0.f;
    int gcur = -1;
    for (int n = base + lane; n < nEnd; n += 16) {
        int g = batch[n];
        if (g != gcur) {
            if (gcur >= 0) {
                atomicAdd(&sp[gcur * 16 + f], acc);
                if (f == 0) atomicAdd(&sc[gcur], cacc);
            }
            gcur = g; acc = 0.f; cacc = 0.f;
        }
        acc += h[(size_t)n * 16 + f];
        cacc += 1.f;
    }
    if (gcur >= 0) {
        atomicAdd(&sp[gcur * 16 + f], acc);
        if (f == 0) atomicAdd(&sc[gcur], cacc);
    }
    __syncthreads();
    for (int i = t; i < NG * 16; i += BS)
        if (sp[i] != 0.f) unsafeAtomicAdd(&pool[i], sp[i]);
    for (int i = t; i < NG; i += BS)
        if (sc[i] != 0.f) unsafeAtomicAdd(&cnt[i], sc[i]);
}

// ---------------- final linear head ----------------
__global__ void final_kernel(const float* __restrict__ pool, const float* __restrict__ cnt,
                             const float* __restrict__ lw, const float* __restrict__ lb,
                             float* __restrict__ out) {
    int idx = threadIdx.x;
    if (idx >= NG * 2) return;
    int g = idx >> 1;
    int c = idx & 1;
    float inv = 1.0f / fmaxf(cnt[g], 1.0f);
    float acc = 0.0f;
#pragma unroll
    for (int f = 0; f < 16; f++) acc += pool[g * 16 + f] * lw[c * 16 + f];
    out[idx] = acc * inv + lb[c];
}

extern "C" void kernel_launch(void* const* d_in, const int* in_sizes, int n_in,
                              void* d_out, int out_size, void* d_ws, size_t ws_size,
                              hipStream_t stream) {
    const float* x    = (const float*)d_in[0];
    const int*   ei   = (const int*)d_in[1];
    const int*   batch= (const int*)d_in[2];
    const float* W1 = (const float*)d_in[3];
    const float* b1 = (const float*)d_in[4];
    const float* g1 = (const float*)d_in[5];
    const float* be1= (const float*)d_in[6];
    const float* m1 = (const float*)d_in[7];
    const float* v1 = (const float*)d_in[8];
    const float* W2 = (const float*)d_in[9];
    const float* b2 = (const float*)d_in[10];
    const float* g2 = (const float*)d_in[11];
    const float* be2= (const float*)d_in[12];
    const float* m2 = (const float*)d_in[13];
    const float* v2 = (const float*)d_in[14];
    const float* W3 = (const float*)d_in[15];
    const float* b3 = (const float*)d_in[16];
    const float* g3 = (const float*)d_in[17];
    const float* be3= (const float*)d_in[18];
    const float* m3 = (const float*)d_in[19];
    const float* v3 = (const float*)d_in[20];
    const float* lw = (const float*)d_in[21];
    const float* lb = (const float*)d_in[22];

    const int* src = ei;            // edge_index[0]
    const int* dst = ei + NE;       // edge_index[1]

    float* ws = (float*)d_ws;
    // ---- workspace layout (4-byte units, offsets kept 16B-aligned) ----
    size_t off = 0;
    float* deg   = ws + off; off += NN;            // 0
    int*   cnt_n = (int*)(ws + off); off += NN;    // histogram
    int*   fill  = (int*)(ws + off); off += NN;    // scatter cursors
    float* pool  = ws + off; off += NG * 16;
    float* cnt   = ws + off; off += NG;
    size_t zero_bytes = off * sizeof(float);       // one memset covers all of the above
    float* w     = ws + off; off += NE;
    int*   rs    = (int*)(ws + off); off += NN + 4;  // row_start [N+1], padded
    int*   col   = (int*)(ws + off); off += NE;
    float* val   = ws + off; off += NE;
    int*   bsum  = (int*)(ws + off); off += 128;
    float* A  = ws + off; off += (size_t)NN * 64;
    float* Bb = ws + off; off += (size_t)NN * 64;
    float* C  = ws + off; off += (size_t)NN * 64;
    float* D  = ws + off; off += (size_t)NN * 32;

    hipMemsetAsync(ws, 0, zero_bytes, stream);

    // ---- edge weights + CSR build ----
    deg_kernel<<<cdiv(NE, BS), BS, 0, stream>>>(src, dst, deg, NE);
    wgt_hist_kernel<<<cdiv(NE, BS), BS, 0, stream>>>(src, dst, deg, w, cnt_n, NE);
    scan1_kernel<<<NB_SCAN, SCAN_BS, 0, stream>>>(cnt_n, rs, bsum, NN);
    scan2_kernel<<<1, 128, 0, stream>>>(bsum, rs + NN, NB_SCAN);
    scan3_kernel<<<cdiv(NN, BS), BS, 0, stream>>>(rs, bsum, NN);
    scatter_kernel<<<cdiv(NE, BS), BS, 0, stream>>>(src, dst, w, rs, fill, col, val, NE);

    // ---- layer 1: 128 -> 64  (U=A, T=Bb, S=C; h1 -> A) ----
    gemm3_kernel<128, 64><<<cdiv((long long)NN * 64, BS), BS, 0, stream>>>(x, W1, A, Bb, C, NN);
    propA_kernel<64><<<cdiv((long long)NN * 16, BS), BS, 0, stream>>>(A, Bb, rs, col, val, NN);
    propC_kernel<64><<<cdiv((long long)NN * 16, BS), BS, 0, stream>>>(Bb, C, rs, col, val,
                                                                      b1, g1, be1, m1, v1, A, NN);
    // ---- layer 2: 64 -> 32  (U=Bb, T=C, S=D; h2 -> Bb) ----
    gemm3_kernel<64, 32><<<cdiv((long long)NN * 32, BS), BS, 0, stream>>>(A, W2, Bb, C, D, NN);
    propA_kernel<32><<<cdiv((long long)NN * 8, BS), BS, 0, stream>>>(Bb, C, rs, col, val, NN);
    propC_kernel<32><<<cdiv((long long)NN * 8, BS), BS, 0, stream>>>(C, D, rs, col, val,
                                                                     b2, g2, be2, m2, v2, Bb, NN);
    // ---- layer 3: 32 -> 16  (U=A, T=C, S=D; h3 -> A) ----
    gemm3_kernel<32, 16><<<cdiv((long long)NN * 16, BS), BS, 0, stream>>>(Bb, W3, A, C, D, NN);
    propA_kernel<16><<<cdiv((long long)NN * 4, BS), BS, 0, stream>>>(A, C, rs, col, val, NN);
    propC_kernel<16><<<cdiv((long long)NN * 4, BS), BS, 0, stream>>>(C, D, rs, col, val,
                                                                     b3, g3, be3, m3, v3, A, NN);
    // ---- pool + head ----
    pool2_kernel<<<cdiv(NN, PNPB), BS, 0, stream>>>(A, batch, pool, cnt, NN);
    final_kernel<<<1, 128, 0, stream>>>(pool, cnt, lw, lb, (float*)d_out);
}

// Round 3
// 584.485 us; speedup vs baseline: 5.4248x; 1.6331x over previous
//
#include <hip/hip_runtime.h>
#include <hip/hip_bf16.h>

// Problem constants (match reference)
#define NN 100000   // nodes
#define NE 640000   // edges
#define NG 64       // graphs
#define BN_EPS 1e-5f

#define BS 256      // block size
#define SCAN_BS 1024
#define NB_SCAN ((NN + SCAN_BS - 1) / SCAN_BS)   // 98
#define PNPB 2048   // nodes per block in pool

static inline int cdiv(long long a, int b) { return (int)((a + b - 1) / b); }

// ---------------- degree: deg[s] += 1 for non-self-loop edges ----------------
__global__ void deg_kernel(const int* __restrict__ src, const int* __restrict__ dst,
                           float* __restrict__ deg, int E) {
    int e = blockIdx.x * blockDim.x + threadIdx.x;
    if (e >= E) return;
    int s = src[e], d = dst[e];
    if (s != d) unsafeAtomicAdd(&deg[s], 1.0f);
}

// ---- edge weights + CSR histogram: w[e] = -dinv[src]*dinv[dst]; cnt_n[dst]++ if w!=0 ----
__global__ void wgt_hist_kernel(const int* __restrict__ src, const int* __restrict__ dst,
                                const float* __restrict__ deg, float* __restrict__ w,
                                int* __restrict__ cnt_n, int E) {
    int e = blockIdx.x * blockDim.x + threadIdx.x;
    if (e >= E) return;
    int s = src[e], d = dst[e];
    float wv = 0.0f;
    if (s != d) {
        float ds_ = deg[s], dd = deg[d];
        float a = ds_ > 0.0f ? rsqrtf(ds_) : 0.0f;
        float b = dd  > 0.0f ? rsqrtf(dd)  : 0.0f;
        wv = -a * b;
    }
    w[e] = wv;
    if (wv != 0.0f) atomicAdd(&cnt_n[d], 1);
}

// ---------------- 3-kernel exclusive scan of cnt_n -> row_start ----------------
__global__ void scan1_kernel(const int* __restrict__ cnt, int* __restrict__ excl,
                             int* __restrict__ bsum, int N) {
    __shared__ int s[SCAN_BS];
    int t = threadIdx.x;
    int i = blockIdx.x * SCAN_BS + t;
    int v = (i < N) ? cnt[i] : 0;
    s[t] = v;
    __syncthreads();
    for (int off = 1; off < SCAN_BS; off <<= 1) {
        int add = (t >= off) ? s[t - off] : 0;
        __syncthreads();
        s[t] += add;
        __syncthreads();
    }
    if (i < N) excl[i] = s[t] - v;   // exclusive
    if (t == SCAN_BS - 1) bsum[blockIdx.x] = s[t];
}

__global__ void scan2_kernel(int* __restrict__ bsum, int* __restrict__ total, int NB) {
    __shared__ int s[128];
    int t = threadIdx.x;
    int v = (t < NB) ? bsum[t] : 0;
    s[t] = v;
    __syncthreads();
    for (int off = 1; off < 128; off <<= 1) {
        int add = (t >= off) ? s[t - off] : 0;
        __syncthreads();
        s[t] += add;
        __syncthreads();
    }
    if (t < NB) bsum[t] = s[t] - v;  // exclusive
    if (t == 127) *total = s[127];
}

__global__ void scan3_kernel(int* __restrict__ excl, const int* __restrict__ bsum, int N) {
    int i = blockIdx.x * blockDim.x + threadIdx.x;
    if (i < N) excl[i] += bsum[i >> 10];   // SCAN_BS = 1024
}

// ---------------- scatter edges into CSR slots ----------------
__global__ void scatter_kernel(const int* __restrict__ src, const int* __restrict__ dst,
                               const float* __restrict__ w, const int* __restrict__ row_start,
                               int* __restrict__ fill, int* __restrict__ col,
                               float* __restrict__ val, int E) {
    int e = blockIdx.x * blockDim.x + threadIdx.x;
    if (e >= E) return;
    float wv = w[e];
    if (wv == 0.0f) return;
    int d = dst[e];
    int pos = row_start[d] + atomicAdd(&fill[d], 1);
    col[pos] = src[e];
    val[pos] = wv;
}

// ------------- tiled gemm3: U = x@W2, T = x@W1, S = x@(W0-W2) -------------
// W layout: [3][FI][FO] row-major.
// Block: 256 threads; thread = (cg = col group of 4, ng = node group of 4).
// LDS: x tile transposed [KT][NPB+4] (pad 4 keeps b128 alignment, <=2-way read
// conflicts); W chunk [3][KT][FO] direct copy. 48 fp32 accumulators/thread.
template <int FI, int FO, int KT>
__global__ __launch_bounds__(256) void gemm3t_kernel(
        const float* __restrict__ x, const float* __restrict__ W,
        float* __restrict__ U, float* __restrict__ T, float* __restrict__ S, int N) {
    constexpr int CG  = FO / 4;        // col groups per node
    constexpr int NGB = 256 / CG;      // node groups per block
    constexpr int NPB = NGB * 4;       // nodes per block
    constexpr int XST = NPB + 4;       // x_lds row stride (floats)
    __shared__ float x_lds[KT * XST];
    __shared__ float w_lds[3 * KT * FO];

    const int t  = threadIdx.x;
    const int cg = t % CG;
    const int ng = t / CG;
    const int n0 = blockIdx.x * NPB;

    float4 acc[3][4];
#pragma unroll
    for (int m = 0; m < 3; m++)
#pragma unroll
        for (int nn = 0; nn < 4; nn++) acc[m][nn] = make_float4(0.f, 0.f, 0.f, 0.f);

    for (int kc = 0; kc < FI / KT; kc++) {
        __syncthreads();
        // ---- stage x chunk (global float4 read -> transposed scalar LDS writes) ----
        constexpr int XQ4 = NPB * KT / 4;
        for (int q = t; q < XQ4; q += 256) {
            int i  = q / (KT / 4);            // node within tile
            int j4 = (q % (KT / 4)) * 4;      // k within chunk
            float4 v = make_float4(0.f, 0.f, 0.f, 0.f);
            if (n0 + i < N)
                v = *(const float4*)(x + (size_t)(n0 + i) * FI + kc * KT + j4);
            x_lds[(j4 + 0) * XST + i] = v.x;
            x_lds[(j4 + 1) * XST + i] = v.y;
            x_lds[(j4 + 2) * XST + i] = v.z;
            x_lds[(j4 + 3) * XST + i] = v.w;
        }
        // ---- stage W chunk (direct copy, coalesced float4) ----
        constexpr int WQ4 = 3 * KT * FO / 4;
        for (int q = t; q < WQ4; q += 256) {
            int qq = q * 4;
            int m  = qq / (KT * FO);
            int r  = qq % (KT * FO);
            float4 v = *(const float4*)(W + (size_t)(m * FI + kc * KT) * FO + r);
            *(float4*)&w_lds[m * KT * FO + r] = v;
        }
        __syncthreads();
        // ---- compute: per k, 4 ds_read_b128 + 48 FMAs ----
#pragma unroll 4
        for (int kk = 0; kk < KT; kk++) {
            const float4 xv = *(const float4*)&x_lds[kk * XST + 4 * ng];
            const float4 w0 = *(const float4*)&w_lds[(0 * KT + kk) * FO + 4 * cg];
            const float4 w1 = *(const float4*)&w_lds[(1 * KT + kk) * FO + 4 * cg];
            const float4 w2 = *(const float4*)&w_lds[(2 * KT + kk) * FO + 4 * cg];
            const float xs[4] = {xv.x, xv.y, xv.z, xv.w};
#pragma unroll
            for (int nn = 0; nn < 4; nn++) {
                float xn = xs[nn];
                acc[0][nn].x = fmaf(xn, w0.x, acc[0][nn].x);
                acc[0][nn].y = fmaf(xn, w0.y, acc[0][nn].y);
                acc[0][nn].z = fmaf(xn, w0.z, acc[0][nn].z);
                acc[0][nn].w = fmaf(xn, w0.w, acc[0][nn].w);
                acc[1][nn].x = fmaf(xn, w1.x, acc[1][nn].x);
                acc[1][nn].y = fmaf(xn, w1.y, acc[1][nn].y);
                acc[1][nn].z = fmaf(xn, w1.z, acc[1][nn].z);
                acc[1][nn].w = fmaf(xn, w1.w, acc[1][nn].w);
                acc[2][nn].x = fmaf(xn, w2.x, acc[2][nn].x);
                acc[2][nn].y = fmaf(xn, w2.y, acc[2][nn].y);
                acc[2][nn].z = fmaf(xn, w2.z, acc[2][nn].z);
                acc[2][nn].w = fmaf(xn, w2.w, acc[2][nn].w);
            }
        }
    }
    // ---- store U = a2, T = a1, S = a0 - a2 ----
#pragma unroll
    for (int nn = 0; nn < 4; nn++) {
        int n = n0 + 4 * ng + nn;
        if (n >= N) continue;
        size_t o = (size_t)n * FO + 4 * cg;
        *(float4*)(U + o) = acc[2][nn];
        *(float4*)(T + o) = acc[1][nn];
        float4 s4;
        s4.x = acc[0][nn].x - acc[2][nn].x;
        s4.y = acc[0][nn].y - acc[2][nn].y;
        s4.z = acc[0][nn].z - acc[2][nn].z;
        s4.w = acc[0][nn].w - acc[2][nn].w;
        *(float4*)(S + o) = s4;
    }
}

// ---------------- propA: inout[i] += 2 * sum_p val[p]*xin[col[p]]  (gather, no atomics) ----
template <int FO>
__global__ void propA_kernel(const float* __restrict__ xin, float* __restrict__ inout,
                             const int* __restrict__ rs, const int* __restrict__ col,
                             const float* __restrict__ val, int N) {
    constexpr int PER = FO / 4;
    int idx = blockIdx.x * blockDim.x + threadIdx.x;
    if (idx >= N * PER) return;
    int i = idx / PER;
    int c = (idx & (PER - 1)) * 4;
    int beg = rs[i], end = rs[i + 1];
    float4 acc = make_float4(0.f, 0.f, 0.f, 0.f);
    for (int p = beg; p < end; ++p) {
        int s = col[p];
        float wv = val[p];
        const float4 xv = *(const float4*)(xin + (size_t)s * FO + c);
        acc.x = fmaf(wv, xv.x, acc.x);
        acc.y = fmaf(wv, xv.y, acc.y);
        acc.z = fmaf(wv, xv.z, acc.z);
        acc.w = fmaf(wv, xv.w, acc.w);
    }
    float4 o = *(const float4*)(inout + (size_t)i * FO + c);
    o.x += 2.0f * acc.x;
    o.y += 2.0f * acc.y;
    o.z += 2.0f * acc.z;
    o.w += 2.0f * acc.w;
    *(float4*)(inout + (size_t)i * FO + c) = o;
}

// ---- propC: h[i] = leaky_relu(BN(S[i] + sum_p val[p]*xin[col[p]] + b)) -- fused epilogue ----
template <int FO>
__global__ void propC_kernel(const float* __restrict__ xin, const float* __restrict__ S,
                             const int* __restrict__ rs, const int* __restrict__ col,
                             const float* __restrict__ val,
                             const float* __restrict__ b, const float* __restrict__ g,
                             const float* __restrict__ be, const float* __restrict__ m,
                             const float* __restrict__ vv,
                             float* __restrict__ h, int N) {
    constexpr int PER = FO / 4;
    int idx = blockIdx.x * blockDim.x + threadIdx.x;
    if (idx >= N * PER) return;
    int i = idx / PER;
    int c = (idx & (PER - 1)) * 4;
    int beg = rs[i], end = rs[i + 1];
    float4 acc = make_float4(0.f, 0.f, 0.f, 0.f);
    for (int p = beg; p < end; ++p) {
        int s = col[p];
        float wv = val[p];
        const float4 xv = *(const float4*)(xin + (size_t)s * FO + c);
        acc.x = fmaf(wv, xv.x, acc.x);
        acc.y = fmaf(wv, xv.y, acc.y);
        acc.z = fmaf(wv, xv.z, acc.z);
        acc.w = fmaf(wv, xv.w, acc.w);
    }
    const float4 sv = *(const float4*)(S + (size_t)i * FO + c);
    float* out = h + (size_t)i * FO + c;
    float4 o;
#pragma unroll
    for (int j = 0; j < 4; j++) {
        int f = c + j;
        float A = g[f] * rsqrtf(vv[f] + BN_EPS);
        float B = be[f] - m[f] * A + b[f] * A;
        float v0 = (j == 0 ? sv.x + acc.x : j == 1 ? sv.y + acc.y : j == 2 ? sv.z + acc.z : sv.w + acc.w);
        float y = v0 * A + B;
        y = y > 0.0f ? y : 0.01f * y;
        (j == 0 ? o.x : j == 1 ? o.y : j == 2 ? o.z : o.w) = y;
    }
    *(float4*)out = o;
}

// ---------------- mean pool: register accum + LDS table + few global atomics ----------------
__global__ void pool2_kernel(const float* __restrict__ h, const int* __restrict__ batch,
                             float* __restrict__ pool, float* __restrict__ cnt, int N) {
    __shared__ float sp[NG * 16];
    __shared__ float sc[NG];
    int t = threadIdx.x;
    for (int i = t; i < NG * 16; i += BS) sp[i] = 0.f;
    for (int i = t; i < NG; i += BS) sc[i] = 0.f;
    __syncthreads();
    int f = t & 15, lane = t >> 4;   // 16 lanes x 16 features
    int base = blockIdx.x * PNPB;
    int nEnd = min(base + PNPB, N);
    float acc = 0.f, cacc = 0.f;
    int gcur = -1;
    for (int n = base + lane; n < nEnd; n += 16) {
        int g = batch[n];
        if (g != gcur) {
            if (gcur >= 0) {
                atomicAdd(&sp[gcur * 16 + f], acc);
                if (f == 0) atomicAdd(&sc[gcur], cacc);
            }
            gcur = g; acc = 0.f; cacc = 0.f;
        }
        acc += h[(size_t)n * 16 + f];
        cacc += 1.f;
    }
    if (gcur >= 0) {
        atomicAdd(&sp[gcur * 16 + f], acc);
        if (f == 0) atomicAdd(&sc[gcur], cacc);
    }
    __syncthreads();
    for (int i = t; i < NG * 16; i += BS)
        if (sp[i] != 0.f) unsafeAtomicAdd(&pool[i], sp[i]);
    for (int i = t; i < NG; i += BS)
        if (sc[i] != 0.f) unsafeAtomicAdd(&cnt[i], sc[i]);
}

// ---------------- final linear head ----------------
__global__ void final_kernel(const float* __restrict__ pool, const float* __restrict__ cnt,
                             const float* __restrict__ lw, const float* __restrict__ lb,
                             float* __restrict__ out) {
    int idx = threadIdx.x;
    if (idx >= NG * 2) return;
    int g = idx >> 1;
    int c = idx & 1;
    float inv = 1.0f / fmaxf(cnt[g], 1.0f);
    float acc = 0.0f;
#pragma unroll
    for (int f = 0; f < 16; f++) acc += pool[g * 16 + f] * lw[c * 16 + f];
    out[idx] = acc * inv + lb[c];
}

extern "C" void kernel_launch(void* const* d_in, const int* in_sizes, int n_in,
                              void* d_out, int out_size, void* d_ws, size_t ws_size,
                              hipStream_t stream) {
    const float* x    = (const float*)d_in[0];
    const int*   ei   = (const int*)d_in[1];
    const int*   batch= (const int*)d_in[2];
    const float* W1 = (const float*)d_in[3];
    const float* b1 = (const float*)d_in[4];
    const float* g1 = (const float*)d_in[5];
    const float* be1= (const float*)d_in[6];
    const float* m1 = (const float*)d_in[7];
    const float* v1 = (const float*)d_in[8];
    const float* W2 = (const float*)d_in[9];
    const float* b2 = (const float*)d_in[10];
    const float* g2 = (const float*)d_in[11];
    const float* be2= (const float*)d_in[12];
    const float* m2 = (const float*)d_in[13];
    const float* v2 = (const float*)d_in[14];
    const float* W3 = (const float*)d_in[15];
    const float* b3 = (const float*)d_in[16];
    const float* g3 = (const float*)d_in[17];
    const float* be3= (const float*)d_in[18];
    const float* m3 = (const float*)d_in[19];
    const float* v3 = (const float*)d_in[20];
    const float* lw = (const float*)d_in[21];
    const float* lb = (const float*)d_in[22];

    const int* src = ei;            // edge_index[0]
    const int* dst = ei + NE;       // edge_index[1]

    float* ws = (float*)d_ws;
    // ---- workspace layout (4-byte units, offsets kept 16B-aligned) ----
    size_t off = 0;
    float* deg   = ws + off; off += NN;            // 0
    int*   cnt_n = (int*)(ws + off); off += NN;    // histogram
    int*   fill  = (int*)(ws + off); off += NN;    // scatter cursors
    float* pool  = ws + off; off += NG * 16;
    float* cnt   = ws + off; off += NG;
    size_t zero_bytes = off * sizeof(float);       // one memset covers all of the above
    float* w     = ws + off; off += NE;
    int*   rs    = (int*)(ws + off); off += NN + 4;  // row_start [N+1], padded
    int*   col   = (int*)(ws + off); off += NE;
    float* val   = ws + off; off += NE;
    int*   bsum  = (int*)(ws + off); off += 128;
    float* A  = ws + off; off += (size_t)NN * 64;
    float* Bb = ws + off; off += (size_t)NN * 64;
    float* C  = ws + off; off += (size_t)NN * 64;
    float* D  = ws + off; off += (size_t)NN * 32;

    hipMemsetAsync(ws, 0, zero_bytes, stream);

    // ---- edge weights + CSR build ----
    deg_kernel<<<cdiv(NE, BS), BS, 0, stream>>>(src, dst, deg, NE);
    wgt_hist_kernel<<<cdiv(NE, BS), BS, 0, stream>>>(src, dst, deg, w, cnt_n, NE);
    scan1_kernel<<<NB_SCAN, SCAN_BS, 0, stream>>>(cnt_n, rs, bsum, NN);
    scan2_kernel<<<1, 128, 0, stream>>>(bsum, rs + NN, NB_SCAN);
    scan3_kernel<<<cdiv(NN, BS), BS, 0, stream>>>(rs, bsum, NN);
    scatter_kernel<<<cdiv(NE, BS), BS, 0, stream>>>(src, dst, w, rs, fill, col, val, NE);

    // ---- layer 1: 128 -> 64  (U=A, T=Bb, S=C; h1 -> A) ----
    gemm3t_kernel<128, 64, 32><<<cdiv(NN, 64), 256, 0, stream>>>(x, W1, A, Bb, C, NN);
    propA_kernel<64><<<cdiv((long long)NN * 16, BS), BS, 0, stream>>>(A, Bb, rs, col, val, NN);
    propC_kernel<64><<<cdiv((long long)NN * 16, BS), BS, 0, stream>>>(Bb, C, rs, col, val,
                                                                      b1, g1, be1, m1, v1, A, NN);
    // ---- layer 2: 64 -> 32  (U=Bb, T=C, S=D; h2 -> Bb) ----
    gemm3t_kernel<64, 32, 32><<<cdiv(NN, 128), 256, 0, stream>>>(A, W2, Bb, C, D, NN);
    propA_kernel<32><<<cdiv((long long)NN * 8, BS), BS, 0, stream>>>(Bb, C, rs, col, val, NN);
    propC_kernel<32><<<cdiv((long long)NN * 8, BS), BS, 0, stream>>>(C, D, rs, col, val,
                                                                     b2, g2, be2, m2, v2, Bb, NN);
    // ---- layer 3: 32 -> 16  (U=A, T=C, S=D; h3 -> A) ----
    gemm3t_kernel<32, 16, 32><<<cdiv(NN, 256), 256, 0, stream>>>(Bb, W3, A, C, D, NN);
    propA_kernel<16><<<cdiv((long long)NN * 4, BS), BS, 0, stream>>>(A, C, rs, col, val, NN);
    propC_kernel<16><<<cdiv((long long)NN * 4, BS), BS, 0, stream>>>(C, D, rs, col, val,
                                                                     b3, g3, be3, m3, v3, A, NN);
    // ---- pool + head ----
    pool2_kernel<<<cdiv(NN, PNPB), BS, 0, stream>>>(A, batch, pool, cnt, NN);
    final_kernel<<<1, 128, 0, stream>>>(pool, cnt, lw, lb, (float*)d_out);
}